// Round 4
// baseline (501.410 us; speedup 1.0000x reference)
//
#include <hip/hip_runtime.h>
#include <cstdint>

// ============================================================================
// QunatEncoderBlock: windowed attention block with int8 fake-quant.
// All qlinear / QK^T / PV matmuls are EXACT in int8xint8->int32 (MFMA i8).
// Rel-pos bias via bf16 MFMA with hi/lo split tables (error ~2^-18).
// R1: k_attn 1-wave/1-tile blocks (grid 13x1200, 64 thr): 152us -> off top5.
// R2: branch-free erf gelu: lin1 99->89us.
// R3: chunk-XOR LDS swizzle (bank conflicts 4.7M->0) + depth-2 vmcnt pipeline
//     -> NULL on time (91us): 2-phase lockstep is the critical path (regime
//     gate: T2/T4 only pay inside an 8-phase schedule).
// R4: k_gemm rewritten as the 8-phase 256^2 template (T3+T4+T2+T5):
//     BM=BN=256, BK=128 i8, 8 waves (2Mx4N), 128KiB LDS double-buffer.
//     Per K-tile: 4 quadrant-phases, each {12 ds_read || stage-next ||
//     barrier; lgkm0; 16 MFMA}; vmcnt(0) only at ph3 on 3-phase-old loads.
//     + bijective XCD-chunked block remap (A-panel L2 locality).
// ============================================================================

typedef int   v4i __attribute__((ext_vector_type(4)));
typedef float v4f __attribute__((ext_vector_type(4)));
typedef short v8s __attribute__((ext_vector_type(8)));
typedef int8_t i8;

__device__ __forceinline__ i8 satq(float x) {   // x already scale-divided
  float q = rintf(x);
  q = fminf(127.f, fmaxf(-128.f, q));
  return (i8)(int)q;
}

__device__ __forceinline__ void gload16(const i8* g, i8* l) {
  __builtin_amdgcn_global_load_lds((const __attribute__((address_space(1))) void*)g,
                                   (__attribute__((address_space(3))) void*)l, 16, 0, 0);
}

__device__ __forceinline__ int pack4(const i8* q) {
  return ((int)(unsigned char)q[0]) | ((int)(unsigned char)q[1] << 8) |
         ((int)(unsigned char)q[2] << 16) | ((int)(unsigned char)q[3] << 24);
}

// branch-free gelu: 0.5*v*(1+erf(v/sqrt2)), erf via A-S 7.1.26 (|err|<=1.5e-7)
__device__ __forceinline__ float fast_gelu(float v) {
  float x = fabsf(v) * 0.70710678118654752f;
  float t = __builtin_amdgcn_rcpf(fmaf(0.3275911f, x, 1.0f));
  float s = fmaf(1.061405429f, t, -1.453152027f);
  s = fmaf(s, t, 1.421413741f);
  s = fmaf(s, t, -0.284496736f);
  s = fmaf(s, t, 0.254829592f);
  s = s * t;
  float e = __expf(-x * x);
  float erfa = fmaf(-s, e, 1.0f);          // erf(|x|)
  float erfs = copysignf(erfa, v);
  float hv = 0.5f * v;
  return fmaf(hv, erfs, hv);
}

// ---------------------------------------------------------------------------
// weight fake-quant -> int8, 16 elements/thread
// ---------------------------------------------------------------------------
__global__ __launch_bounds__(256) void k_wquant(const float* __restrict__ w,
                                                i8* __restrict__ o, int n16,
                                                const float* __restrict__ wsc, int sidx) {
  int i = blockIdx.x * 256 + threadIdx.x;
  if (i >= n16) return;
  float inv = 1.0f / wsc[sidx];
  const float4* src = (const float4*)w + (size_t)i * 4;
  i8 buf[16];
#pragma unroll
  for (int t = 0; t < 4; t++) {
    float4 f = src[t];
    buf[t*4+0] = satq(f.x * inv); buf[t*4+1] = satq(f.y * inv);
    buf[t*4+2] = satq(f.z * inv); buf[t*4+3] = satq(f.w * inv);
  }
  *(v4i*)(o + (size_t)i * 16) = *(v4i*)buf;
}

// ---------------------------------------------------------------------------
// pack rel-pos tables for bf16 MFMA B-operand, hi/lo split.
// ---------------------------------------------------------------------------
__global__ __launch_bounds__(256) void k_relpack(const float* __restrict__ rph,
    const float* __restrict__ rpw, short* __restrict__ TB) {
  int g = blockIdx.x * 256 + threadIdx.x;
  if (g >= 1024) return;
  int lane = g & 63, c = g >> 6;
  int p = c & 1, ks = (c >> 1) & 1, nt = (c >> 2) & 1, tb = c >> 3;
  const float* src = tb ? rpw : rph;
  int n = nt * 16 + (lane & 15);
  int k0 = ks * 32 + (lane >> 4) * 8;
  short outv[8];
#pragma unroll
  for (int j = 0; j < 8; j++) {
    float v = (n < 27) ? src[n * 64 + k0 + j] : 0.f;
    unsigned u = __float_as_uint(v);
    unsigned hi = (u + 0x7fffu + ((u >> 16) & 1u)) >> 16;
    if (p == 0) outv[j] = (short)hi;
    else {
      float lof = v - __uint_as_float(hi << 16);
      unsigned ul = __float_as_uint(lof);
      outv[j] = (short)((ul + 0x7fffu + ((ul >> 16) & 1u)) >> 16);
    }
  }
  *(v8s*)(TB + (size_t)c * 512 + lane * 8) = *(v8s*)outv;
}

// ---------------------------------------------------------------------------
// LN1: wave per window-token (pad 64->70, 5x5 windows of 14x14), quant a_s[4]
// ---------------------------------------------------------------------------
__global__ __launch_bounds__(256) void k_ln1(const float* __restrict__ x,
    const float* __restrict__ w, const float* __restrict__ b,
    const float* __restrict__ as, i8* __restrict__ outq) {
  int wt = blockIdx.x * 4 + (threadIdx.x >> 6);
  int lane = threadIdx.x & 63;
  int win = wt / 196, tok = wt - win * 196;
  int bb = win / 25, wrem = win - bb * 25, wh = wrem / 5, ww = wrem - wh * 5;
  int r = tok / 14, c = tok - r * 14;
  int y = wh * 14 + r, xx = ww * 14 + c;
  i8* dst = outq + (size_t)wt * 768 + lane * 12;
  if (y >= 64 || xx >= 64) {
    ((int*)dst)[0] = 0; ((int*)dst)[1] = 0; ((int*)dst)[2] = 0;
    return;
  }
  const float* row = x + (((size_t)bb * 64 + y) * 64 + xx) * 768 + lane * 12;
  float v[12];
  *(float4*)(v)     = *(const float4*)(row);
  *(float4*)(v + 4) = *(const float4*)(row + 4);
  *(float4*)(v + 8) = *(const float4*)(row + 8);
  float s = 0.f, ss = 0.f;
#pragma unroll
  for (int j = 0; j < 12; j++) { s += v[j]; ss += v[j] * v[j]; }
#pragma unroll
  for (int off = 1; off < 64; off <<= 1) { s += __shfl_xor(s, off); ss += __shfl_xor(ss, off); }
  float mu = s * (1.0f / 768.0f);
  float var = ss * (1.0f / 768.0f) - mu * mu;
  float rstd = 1.0f / sqrtf(var + 1e-6f);
  float inv = 1.0f / as[4];
  float wv[12], bv[12];
  *(float4*)(wv)     = *(const float4*)(w + lane * 12);
  *(float4*)(wv + 4) = *(const float4*)(w + lane * 12 + 4);
  *(float4*)(wv + 8) = *(const float4*)(w + lane * 12 + 8);
  *(float4*)(bv)     = *(const float4*)(b + lane * 12);
  *(float4*)(bv + 4) = *(const float4*)(b + lane * 12 + 4);
  *(float4*)(bv + 8) = *(const float4*)(b + lane * 12 + 8);
  i8 q[12];
#pragma unroll
  for (int j = 0; j < 12; j++) q[j] = satq(((v[j] - mu) * rstd * wv[j] + bv[j]) * inv);
  ((int*)dst)[0] = pack4(q); ((int*)dst)[1] = pack4(q + 4); ((int*)dst)[2] = pack4(q + 8);
}

// ---------------------------------------------------------------------------
// LN2: wave per token, quant a_s[6]
// ---------------------------------------------------------------------------
__global__ __launch_bounds__(256) void k_ln2(const float* __restrict__ x2,
    const float* __restrict__ w, const float* __restrict__ b,
    const float* __restrict__ as, i8* __restrict__ outq) {
  int tokg = blockIdx.x * 4 + (threadIdx.x >> 6);
  int lane = threadIdx.x & 63;
  const float* row = x2 + (size_t)tokg * 768 + lane * 12;
  float v[12];
  *(float4*)(v)     = *(const float4*)(row);
  *(float4*)(v + 4) = *(const float4*)(row + 4);
  *(float4*)(v + 8) = *(const float4*)(row + 8);
  float s = 0.f, ss = 0.f;
#pragma unroll
  for (int j = 0; j < 12; j++) { s += v[j]; ss += v[j] * v[j]; }
#pragma unroll
  for (int off = 1; off < 64; off <<= 1) { s += __shfl_xor(s, off); ss += __shfl_xor(ss, off); }
  float mu = s * (1.0f / 768.0f);
  float var = ss * (1.0f / 768.0f) - mu * mu;
  float rstd = 1.0f / sqrtf(var + 1e-6f);
  float inv = 1.0f / as[6];
  float wv[12], bv[12];
  *(float4*)(wv)     = *(const float4*)(w + lane * 12);
  *(float4*)(wv + 4) = *(const float4*)(w + lane * 12 + 4);
  *(float4*)(wv + 8) = *(const float4*)(w + lane * 12 + 8);
  *(float4*)(bv)     = *(const float4*)(b + lane * 12);
  *(float4*)(bv + 4) = *(const float4*)(b + lane * 12 + 4);
  *(float4*)(bv + 8) = *(const float4*)(b + lane * 12 + 8);
  i8* dst = outq + (size_t)tokg * 768 + lane * 12;
  i8 q[12];
#pragma unroll
  for (int j = 0; j < 12; j++) q[j] = satq(((v[j] - mu) * rstd * wv[j] + bv[j]) * inv);
  ((int*)dst)[0] = pack4(q); ((int*)dst)[1] = pack4(q + 4); ((int*)dst)[2] = pack4(q + 8);
}

// ---------------------------------------------------------------------------
// int8 GEMM, 8-phase 256x256 schedule. C[M,N] = A[M,K] x B[N,K]^T.
// BK=128, 8 waves (2M x 4N), per-wave out 128x64, LDS 128KiB (2 dbuf).
// Requires N%256==0, K%256==0 (even # of 128-K-tiles). M tail clamped/guarded.
// Per K-tile tau (4 phases = C quadrants):
//   ph0: ds_read q0 | stage(tau+1 -> other dbuf); BAR; lgkm0; 16 MFMA; BAR
//   ph1/ph2: ds_read q1/q2; BAR; lgkm0; MFMA; BAR
//   ph3: ds_read q3; vmcnt(0) [loads 3 phases old]; BAR; lgkm0; MFMA; BAR
// Swizzle: LDS[r][c] = glob[r][c ^ ((r>>1)&7)] (src pre-swizzled, read XOR'd).
// Epi::store4(a, m, n0): a[r] = C[m][n0+r], n0%4==0, m<M guaranteed.
// ---------------------------------------------------------------------------
#define PHASE(d, ih, jh, DOSTAGE, DOVM)                                        \
  {                                                                            \
    v4i af[4][2], bf[2][2];                                                    \
    _Pragma("unroll") for (int i = 0; i < 4; i++)                              \
      _Pragma("unroll") for (int kk = 0; kk < 2; kk++)                         \
        af[i][kk] = *(const v4i*)(LA[d] +                                      \
            (wm * 128 + ((ih) * 4 + i) * 16 + lc) * 128 +                      \
            (((kk * 4 + quad) ^ xsw) * 16));                                   \
    _Pragma("unroll") for (int j = 0; j < 2; j++)                              \
      _Pragma("unroll") for (int kk = 0; kk < 2; kk++)                         \
        bf[j][kk] = *(const v4i*)(LB[d] +                                      \
            (wn * 64 + ((jh) * 2 + j) * 16 + lc) * 128 +                       \
            (((kk * 4 + quad) ^ xsw) * 16));                                   \
    if (DOSTAGE) {                                                             \
      _Pragma("unroll") for (int s = 0; s < 4; s++) {                          \
        gload16(pA[s], LA[(d) ^ 1] + s * 8192 + tid * 16); pA[s] += 128; }     \
      _Pragma("unroll") for (int s = 0; s < 4; s++) {                          \
        gload16(pB[s], LB[(d) ^ 1] + s * 8192 + tid * 16); pB[s] += 128; }     \
    }                                                                          \
    if (DOVM) { asm volatile("s_waitcnt vmcnt(0)" ::: "memory"); }             \
    __builtin_amdgcn_sched_barrier(0);                                         \
    __builtin_amdgcn_s_barrier();                                              \
    asm volatile("s_waitcnt lgkmcnt(0)" ::: "memory");                         \
    __builtin_amdgcn_sched_barrier(0);                                         \
    __builtin_amdgcn_s_setprio(1);                                             \
    _Pragma("unroll") for (int i = 0; i < 4; i++)                              \
      _Pragma("unroll") for (int j = 0; j < 2; j++)                            \
        _Pragma("unroll") for (int kk = 0; kk < 2; kk++)                       \
          acc[(ih) * 4 + i][(jh) * 2 + j] =                                    \
              __builtin_amdgcn_mfma_i32_16x16x64_i8(                           \
                  bf[j][kk], af[i][kk], acc[(ih) * 4 + i][(jh) * 2 + j],       \
                  0, 0, 0);                                                    \
    __builtin_amdgcn_s_setprio(0);                                             \
    __builtin_amdgcn_sched_barrier(0);                                         \
    __builtin_amdgcn_s_barrier();                                              \
  }

#define GROUP(d, hn)          \
  PHASE(d, 0, 0, (hn), false) \
  PHASE(d, 0, 1, false, false)\
  PHASE(d, 1, 0, false, false)\
  PHASE(d, 1, 1, false, (hn))

template <class Epi>
__global__ __launch_bounds__(512) void k_gemm(const i8* __restrict__ A, const i8* __restrict__ B,
                                              int M, int N, int K, int nbx, Epi epi) {
  __shared__ __align__(16) i8 LA[2][32768];
  __shared__ __align__(16) i8 LB[2][32768];
  const int tid = threadIdx.x;
  const int lane = tid & 63, wave = tid >> 6;
  const int quad = lane >> 4, lc = lane & 15;
  const int xsw = lc >> 1;                  // read-side XOR (= f(row) per-lane)
  const int wm = wave >> 2, wn = wave & 3;  // 2 M-waves x 4 N-waves

  // bijective XCD-chunked remap (m204), bx fastest -> A-panel locality per XCD
  const int nwg = gridDim.x;
  const int orig = blockIdx.x;
  const int qch = nwg >> 3, rch = nwg & 7;
  const int xcd = orig & 7, idx = orig >> 3;
  const int wg = (xcd < rch ? xcd * (qch + 1) : rch * (qch + 1) + (xcd - rch) * qch) + idx;
  const int bx = wg % nbx, by = wg / nbx;
  const long bm = (long)by * 256, bn = (long)bx * 256;

  const v4i vz = {0, 0, 0, 0};
  v4i acc[8][4];
#pragma unroll
  for (int i = 0; i < 8; i++)
#pragma unroll
    for (int j = 0; j < 4; j++) acc[i][j] = vz;

  // staging: thread covers rows rbase+64s (s=0..3), chunk c0=tid&7, with the
  // source chunk pre-swizzled: cs = c0 ^ f(row), f(row)=(row>>1)&7 = (tid>>4)&7
  const int rbase = tid >> 3, c0 = tid & 7;
  const int cs = c0 ^ ((tid >> 4) & 7);
  const i8* pA[4];
  const i8* pB[4];
#pragma unroll
  for (int s = 0; s < 4; s++) {
    long rA = bm + rbase + 64 * s; if (rA >= M) rA = 0;
    pA[s] = A + rA * (size_t)K + cs * 16;
    pB[s] = B + (bn + rbase + 64 * s) * (size_t)K + cs * 16;
  }

  // prologue: stage tile 0 into dbuf 0, drain, barrier
#pragma unroll
  for (int s = 0; s < 4; s++) { gload16(pA[s], LA[0] + s * 8192 + tid * 16); pA[s] += 128; }
#pragma unroll
  for (int s = 0; s < 4; s++) { gload16(pB[s], LB[0] + s * 8192 + tid * 16); pB[s] += 128; }
  asm volatile("s_waitcnt vmcnt(0)" ::: "memory");
  __builtin_amdgcn_s_barrier();

  const int NT = K >> 7;                    // # of 128-wide K-tiles (even)
  for (int t = 0; t < NT; t += 2) {
    GROUP(0, true)                          // compute tile t, stage t+1
    bool hn = (t + 2 < NT);
    GROUP(1, hn)                            // compute tile t+1, stage t+2
  }

  Epi e = epi;
  e.init();
#pragma unroll
  for (int i = 0; i < 8; i++) {
    int gm = (int)bm + wm * 128 + i * 16 + lc;           // M row
#pragma unroll
    for (int j = 0; j < 4; j++) {
      int gn0 = (int)bn + wn * 64 + j * 16 + quad * 4;   // N col (4 consecutive)
      if (gm < M) e.store4(acc[i][j], gm, gn0);
    }
  }
}
#undef PHASE
#undef GROUP

// -------- epilogues: store4(a, m, n0) with a[r] = C[m][n0+r], n0%4==0 ----
struct EpiQKV {   // split into q,k (token-major) and v^T (ch-major, stride 256)
  const float* as; const float* wsc; const float* bias;
  i8 *qq, *kq, *vt;
  float sab, invq, invk, invv;
  __device__ void init() {
    sab = as[4] * wsc[0]; invq = 1.f / as[0]; invk = 1.f / as[1]; invv = 1.f / as[2];
  }
  __device__ void store4(const v4i a, int m, int n0) {
    int t = n0 / 768, rem = n0 - t * 768;
    int head = rem >> 6, ch0 = rem & 63;              // ch0%4==0: same head for all 4
    int win = m / 196, tok = m - win * 196;
    size_t bh = (size_t)win * 12 + head;
    float4 bv = *(const float4*)(bias + n0);
    const float* bp = (const float*)&bv;
    if (t == 2) {
#pragma unroll
      for (int r = 0; r < 4; r++)
        vt[(bh * 64 + ch0 + r) * 256 + tok] = satq(((float)a[r] * sab + bp[r]) * invv);
    } else {
      float inv = (t == 0) ? invq : invk;
      i8 q[4];
#pragma unroll
      for (int r = 0; r < 4; r++) q[r] = satq(((float)a[r] * sab + bp[r]) * inv);
      *(int*)((t == 0 ? qq : kq) + (bh * 196 + tok) * 64 + ch0) = pack4(q);
    }
  }
};

struct EpiProj {  // window reverse + unpad + shortcut add -> x2 (in d_out)
  const float* as; const float* wsc; const float* bias; const float* x0; float* out;
  float sab;
  __device__ void init() { sab = as[5] * wsc[1]; }
  __device__ void store4(const v4i a, int m, int n0) {
    int win = m / 196, tok = m - win * 196;
    int bb = win / 25, wrem = win - bb * 25, wh = wrem / 5, ww = wrem - wh * 5;
    int rr = tok / 14, cc = tok - rr * 14;
    int y = wh * 14 + rr, xx = ww * 14 + cc;
    if (y >= 64 || xx >= 64) return;
    size_t o = (((size_t)bb * 64 + y) * 64 + xx) * 768 + n0;
    float4 bv = *(const float4*)(bias + n0);
    float4 xv = *(const float4*)(x0 + o);
    float4 ov;
    ov.x = (float)a[0] * sab + bv.x + xv.x;
    ov.y = (float)a[1] * sab + bv.y + xv.y;
    ov.z = (float)a[2] * sab + bv.z + xv.z;
    ov.w = (float)a[3] * sab + bv.w + xv.w;
    *(float4*)(out + o) = ov;
  }
};

struct EpiLin1 {  // bias + branch-free gelu + quant a_s[7]
  const float* as; const float* wsc; const float* bias; i8* outq;
  float sab, invg;
  __device__ void init() { sab = as[6] * wsc[2]; invg = 1.f / as[7]; }
  __device__ void store4(const v4i a, int m, int n0) {
    float4 bv = *(const float4*)(bias + n0);
    const float* bp = (const float*)&bv;
    i8 q[4];
#pragma unroll
    for (int r = 0; r < 4; r++) {
      float v = fmaf((float)a[r], sab, bp[r]);
      q[r] = satq(fast_gelu(v) * invg);
    }
    *(int*)(outq + (size_t)m * 3072 + n0) = pack4(q);
  }
};

struct EpiLin2 {  // bias + residual add into d_out
  const float* as; const float* wsc; const float* bias; float* out;
  float sab;
  __device__ void init() { sab = as[7] * wsc[3]; }
  __device__ void store4(const v4i a, int m, int n0) {
    size_t o = (size_t)m * 768 + n0;
    float4 bv = *(const float4*)(bias + n0);
    float4 ov = *(const float4*)(out + o);
    ov.x += (float)a[0] * sab + bv.x;
    ov.y += (float)a[1] * sab + bv.y;
    ov.z += (float)a[2] * sab + bv.z;
    ov.w += (float)a[3] * sab + bv.w;
    *(float4*)(out + o) = ov;
  }
};

// ---------------------------------------------------------------------------
// attention: ONE WAVE per (win*12+head, 16-row tile). Grid (13, 1200), 64 thr.
// ---------------------------------------------------------------------------
__global__ __launch_bounds__(64, 4) void k_attn(const i8* __restrict__ qq, const i8* __restrict__ kq,
    const i8* __restrict__ vt, const short* __restrict__ TB,
    const float* __restrict__ as, i8* __restrict__ outq) {
  __shared__ __align__(16) i8 Ps[16 * 272];       // this wave's P tile
  __shared__ float relS[16][66];                  // rel bias [row][d(h)|32+d(w)]
  const int t = blockIdx.x, bh = blockIdx.y;
  const int win = bh / 12, head = bh - win * 12;
  const int lane = threadIdx.x;
  const int quad = lane >> 4, lc = lane & 15;
  const float s0 = as[0];
  const float ssc = s0 * as[1] * 0.125f;
  const float invs3 = 1.0f / as[3];
  const float oscale = as[2] * as[3] / as[5];

  // zero pad cols [192,256)
  for (int idx = lane; idx < 256; idx += 64)
    *(int*)(Ps + (idx >> 4) * 272 + 192 + (idx & 15) * 4) = 0;

  // per-lane col decomposition, byte-packed (kh,kw <= 13)
  unsigned ckhp[4] = {0, 0, 0, 0}, ckwp[4] = {0, 0, 0, 0};
#pragma unroll
  for (int f = 0; f < 13; f++) {
    int col = f * 16 + lc; if (col > 195) col = 195;
    int kh = col / 14, kw = col - kh * 14;
    ckhp[f >> 2] |= (unsigned)kh << ((f & 3) * 8);
    ckwp[f >> 2] |= (unsigned)kw << ((f & 3) * 8);
  }

  const v8s* TBv = (const v8s*)TB;
  const v4i vz = {0, 0, 0, 0};

  // ---- rel-pos bias via bf16 MFMA ----
  {
    int arow = t * 16 + lc; if (arow > 195) arow = 195;
    const i8* qrow = qq + ((size_t)bh * 196 + arow) * 64;
    v8s af[2];
#pragma unroll
    for (int ks = 0; ks < 2; ks++) {
      const i8* p = qrow + ks * 32 + quad * 8;
#pragma unroll
      for (int j = 0; j < 8; j++)
        af[ks][j] = (short)(__float_as_uint((float)p[j]) >> 16);  // exact int->bf16
    }
    v4f rh0 = {0,0,0,0}, rh1 = {0,0,0,0}, rw0 = {0,0,0,0}, rw1 = {0,0,0,0};
#pragma unroll
    for (int ks = 0; ks < 2; ks++)
#pragma unroll
      for (int p2 = 0; p2 < 2; p2++) {
        rh0 = __builtin_amdgcn_mfma_f32_16x16x32_bf16(af[ks], TBv[(0*4 + ks*2 + p2)*64 + lane], rh0, 0, 0, 0);
        rh1 = __builtin_amdgcn_mfma_f32_16x16x32_bf16(af[ks], TBv[(1*4 + ks*2 + p2)*64 + lane], rh1, 0, 0, 0);
        rw0 = __builtin_amdgcn_mfma_f32_16x16x32_bf16(af[ks], TBv[(2*4 + ks*2 + p2)*64 + lane], rw0, 0, 0, 0);
        rw1 = __builtin_amdgcn_mfma_f32_16x16x32_bf16(af[ks], TBv[(3*4 + ks*2 + p2)*64 + lane], rw1, 0, 0, 0);
      }
#pragma unroll
    for (int r = 0; r < 4; r++) {
      int rl = quad * 4 + r;
      relS[rl][lc]      = rh0[r] * s0;
      relS[rl][16 + lc] = rh1[r] * s0;
      relS[rl][32 + lc] = rw0[r] * s0;
      relS[rl][48 + lc] = rw1[r] * s0;
    }
  }

  // ---- QK^T (int-exact) ----
  v4i aq = *(const v4i*)(qq + ((size_t)bh * 196 + t * 16 + lc) * 64 + quad * 16);
  v4i sacc[13];
#pragma unroll
  for (int f = 0; f < 13; f++) {
    v4i bk = *(const v4i*)(kq + ((size_t)bh * 196 + f * 16 + lc) * 64 + quad * 16);
    sacc[f] = __builtin_amdgcn_mfma_i32_16x16x64_i8(aq, bk, vz, 0, 0, 0);
  }

  // ---- softmax + P quant ----
#pragma unroll
  for (int r = 0; r < 4; r++) {
    int rl = quad * 4 + r;
    int row = t * 16 + rl;
    int qh = row / 14, qw = row - qh * 14;
    const float* rH = &relS[rl][13 + qh];        // rH[-kh]
    const float* rW = &relS[rl][32 + 13 + qw];   // rW[-kw]
    float L[13];
#pragma unroll
    for (int f = 0; f < 13; f++) {
      int kh = (int)((ckhp[f >> 2] >> ((f & 3) * 8)) & 0xffu);
      int kw = (int)((ckwp[f >> 2] >> ((f & 3) * 8)) & 0xffu);
      L[f] = ((f < 12) | (lc < 4)) ? fmaf((float)sacc[f][r], ssc, rH[-kh] + rW[-kw]) : -1e30f;
    }
    float mx = L[0];
#pragma unroll
    for (int f = 1; f < 13; f++) mx = fmaxf(mx, L[f]);
#pragma unroll
    for (int off = 1; off < 16; off <<= 1) mx = fmaxf(mx, __shfl_xor(mx, off));
    float sum = 0.f;
#pragma unroll
    for (int f = 0; f < 13; f++) { float e = __expf(L[f] - mx); L[f] = e; sum += e; }
#pragma unroll
    for (int off = 1; off < 16; off <<= 1) sum += __shfl_xor(sum, off);
    float cq = (1.0f / sum) * invs3;
#pragma unroll
    for (int f = 0; f < 13; f++)
      Ps[rl * 272 + f * 16 + lc] = satq(L[f] * cq);
  }

  // ---- PV (int-exact) ----
  v4i oacc[4];
#pragma unroll
  for (int nt = 0; nt < 4; nt++) oacc[nt] = vz;
#pragma unroll
  for (int kc = 0; kc < 4; kc++) {
    v4i ap = *(const v4i*)(Ps + lc * 272 + kc * 64 + quad * 16);
#pragma unroll
    for (int nt = 0; nt < 4; nt++) {
      v4i bv = *(const v4i*)(vt + ((size_t)bh * 64 + nt * 16 + lc) * 256 + kc * 64 + quad * 16);
      oacc[nt] = __builtin_amdgcn_mfma_i32_16x16x64_i8(ap, bv, oacc[nt], 0, 0, 0);
    }
  }
#pragma unroll
  for (int nt = 0; nt < 4; nt++) {
    int ch = nt * 16 + lc;
#pragma unroll
    for (int r = 0; r < 4; r++) {
      int row = t * 16 + quad * 4 + r;
      if (row < 196)
        outq[((size_t)win * 196 + row) * 768 + head * 64 + ch] = satq((float)oacc[nt][r] * oscale);
    }
  }
}

// ---------------------------------------------------------------------------
extern "C" void kernel_launch(void* const* d_in, const int* in_sizes, int n_in,
                              void* d_out, int out_size, void* d_ws, size_t ws_size,
                              hipStream_t stream) {
  const float* x     = (const float*)d_in[0];
  const float* ln1w  = (const float*)d_in[1];
  const float* ln1b  = (const float*)d_in[2];
  const float* ln2w  = (const float*)d_in[3];
  const float* ln2b  = (const float*)d_in[4];
  const float* qkvw  = (const float*)d_in[5];
  const float* qkvb  = (const float*)d_in[6];
  const float* projw = (const float*)d_in[7];
  const float* projb = (const float*)d_in[8];
  const float* lin1w = (const float*)d_in[9];
  const float* lin1b = (const float*)d_in[10];
  const float* lin2w = (const float*)d_in[11];
  const float* lin2b = (const float*)d_in[12];
  const float* rph   = (const float*)d_in[13];
  const float* rpw   = (const float*)d_in[14];
  const float* as    = (const float*)d_in[15];
  const float* wsc   = (const float*)d_in[16];
  float* out = (float*)d_out;

  // ws layout (72,462,336 B total), regions reused across stages:
  char* ws = (char*)d_ws;
  i8* big    = (i8*)ws;                          // 50,331,648
  i8* qq     = big;                              // 15,052,800 (1200*196*64)
  i8* kq     = big + 15052800;                   // 15,052,800
  i8* vt     = big + 30105600;                   // 19,660,800 (1200*64*256)
  short* TB  = (short*)(big + 49766400);         //     16,384 (rel tables; dead before lin1)
  i8* mlpq   = big;                              // 50,331,648 (16384*3072), after attn
  i8* creg   = (i8*)(ws + 50331648);             // 15,052,800
  i8* winq   = creg;                             // qkv input
  i8* attno  = creg;                             // proj input (after qkv dead)
  i8* yq     = creg;                             // lin1 input (after proj dead)
  i8* wqb    = (i8*)(ws + 65384448);             //  7,077,888
  i8* qkvwq  = wqb;
  i8* projwq = wqb + 1769472;
  i8* lin1wq = projwq + 589824;
  i8* lin2wq = lin1wq + 2359296;

  k_wquant<<<(110592 + 255) / 256, 256, 0, stream>>>(qkvw,  qkvwq,  110592, wsc, 0);
  k_wquant<<<( 36864 + 255) / 256, 256, 0, stream>>>(projw, projwq,  36864, wsc, 1);
  k_wquant<<<(147456 + 255) / 256, 256, 0, stream>>>(lin1w, lin1wq, 147456, wsc, 2);
  k_wquant<<<(147456 + 255) / 256, 256, 0, stream>>>(lin2w, lin2wq, 147456, wsc, 3);
  k_relpack<<<4, 256, 0, stream>>>(rph, rpw, TB);

  k_ln1<<<4900, 256, 0, stream>>>(x, ln1w, ln1b, as, winq);

  { EpiQKV e{as, wsc, qkvb, qq, kq, vt};
    k_gemm<EpiQKV><<<693, 512, 0, stream>>>(winq, qkvwq, 19600, 2304, 768, 9, e); }   // 77x9

  k_attn<<<dim3(13, 1200), 64, 0, stream>>>(qq, kq, vt, TB, as, attno);

  { EpiProj e{as, wsc, projb, x, out};
    k_gemm<EpiProj><<<231, 512, 0, stream>>>(attno, projwq, 19600, 768, 768, 3, e); } // 77x3

  k_ln2<<<4096, 256, 0, stream>>>(out, ln2w, ln2b, as, yq);

  { EpiLin1 e{as, wsc, lin1b, mlpq};
    k_gemm<EpiLin1><<<768, 512, 0, stream>>>(yq, lin1wq, 16384, 3072, 768, 12, e); }  // 64x12

  { EpiLin2 e{as, wsc, lin2b, out};
    k_gemm<EpiLin2><<<192, 512, 0, stream>>>(mlpq, lin2wq, 16384, 768, 3072, 3, e); } // 64x3
}